// Round 4
// baseline (1656.786 us; speedup 1.0000x reference)
//
#include <hip/hip_runtime.h>

typedef unsigned short u16;
typedef unsigned int u32;
using bf8 = __attribute__((ext_vector_type(8))) short;  // 8 bf16 (4 VGPRs)
using f4  = __attribute__((ext_vector_type(4))) float;  // MFMA acc

#define DEV __device__ __forceinline__

// B=2, S=2048, HID=4096, H=32, KV=8, D=128, G=4
// q scale folded into rope: (1/sqrt(128)) * log2(e)  -> softmax in exp2 domain
#define QSCALE (0.08838834764831845f * 1.4426950408889634f)

DEV u16 f2b(float f) {            // RNE fp32 -> bf16 bits
  u32 u = __float_as_uint(f);
  u32 r = u + 0x7fff + ((u >> 16) & 1);
  return (u16)(r >> 16);
}
DEV u32 f2b_u(u32 u) {            // RNE from fp32 bits
  return (u + 0x7fff + ((u >> 16) & 1)) >> 16;
}
DEV float b2f(u32 bits) { return __uint_as_float(bits << 16); }

#define GLOAD16(g, l)                                                          \
  __builtin_amdgcn_global_load_lds((__attribute__((address_space(1))) u32*)(g),\
                                   (__attribute__((address_space(3))) u32*)(l),\
                                   16, 0, 0)

DEV f4 mfma16(bf8 a, bf8 b, f4 c) {
  return __builtin_amdgcn_mfma_f32_16x16x32_bf16(a, b, c, 0, 0, 0);
}

// =====================================================================
// Input normalizer: copies src -> dst as bf16. Detects src dtype at
// runtime from probe[0] (cos[0]==1.0: fp32 -> 0x3F800000, bf16 -> 0x3F803F80).
// n8 = element count / 8.
// =====================================================================
__global__ __launch_bounds__(256) void convert_kernel(
    const u16* __restrict__ src, u16* __restrict__ dst,
    const u32* __restrict__ probe, int n8) {
  const int t = blockIdx.x * 256 + threadIdx.x;
  if (t >= n8) return;
  const bool isf32 = (probe[0] == 0x3F800000u);
  const uint4* s4 = (const uint4*)src;
  uint4* d4 = (uint4*)dst;
  if (!isf32) {
    d4[t] = s4[t];
    return;
  }
  uint4 a = s4[2 * t];
  uint4 b = s4[2 * t + 1];
  uint4 o;
  o.x = f2b_u(a.x) | (f2b_u(a.y) << 16);
  o.y = f2b_u(a.z) | (f2b_u(a.w) << 16);
  o.z = f2b_u(b.x) | (f2b_u(b.y) << 16);
  o.w = f2b_u(b.z) | (f2b_u(b.w) << 16);
  d4[t] = o;
}

// =====================================================================
// GEMM core: C[128x128 tile] = A(M x K, rm) * W(N x K, rm)^T  (m97 pattern)
// =====================================================================
DEV void gemm_core(const u16* __restrict__ A, const u16* __restrict__ W,
                   int lda, int ldw, int K, int mb, int nb,
                   u16* As, u16* Bs, f4 (&acc)[4][4]) {
  const int tid = threadIdx.x;
  const int lane = tid & 63;
  const int wid = tid >> 6;
  const int l16 = lane & 15;
  const int quad = lane >> 4;
  const int wm = (wid >> 1) * 64;
  const int wn = (wid & 1) * 64;

  const int c0 = wid * 2;
  const int rowA0 = c0 * 16 + (lane >> 2);
  const int colb = (lane & 3) * 16;

  const char* gA = (const char*)(A + (size_t)(mb * 128 + rowA0) * lda) + colb;
  const char* gB = (const char*)(W + (size_t)(nb * 128 + rowA0) * ldw) + colb;
  char* lA = (char*)As + c0 * 1024;
  char* lB = (char*)Bs + c0 * 1024;
  const size_t strideA = (size_t)lda * 32;
  const size_t strideB = (size_t)ldw * 32;

  for (int k0 = 0; k0 < K; k0 += 32) {
    __syncthreads();
    GLOAD16(gA + (size_t)k0 * 2, lA);
    GLOAD16(gA + (size_t)k0 * 2 + strideA, lA + 1024);
    GLOAD16(gB + (size_t)k0 * 2, lB);
    GLOAD16(gB + (size_t)k0 * 2 + strideB, lB + 1024);
    __syncthreads();

    bf8 af[4], bw[4];
#pragma unroll
    for (int t = 0; t < 4; t++) {
      af[t] = *(const bf8*)(As + (wm + t * 16 + l16) * 32 + quad * 8);
      bw[t] = *(const bf8*)(Bs + (wn + t * 16 + l16) * 32 + quad * 8);
    }
#pragma unroll
    for (int mt = 0; mt < 4; mt++)
#pragma unroll
      for (int nt = 0; nt < 4; nt++)
        acc[mt][nt] = mfma16(af[mt], bw[nt], acc[mt][nt]);
  }
}

// =====================================================================
// Fused QKV projection. grid (32, 48): y<32 -> Q, y<40 -> K, else V.
// V written transposed: vt[(b*KV+kv)*D + d][s].
// =====================================================================
__global__ __launch_bounds__(256) void gemm_qkv_kernel(
    const u16* __restrict__ hidden, const u16* __restrict__ wq,
    const u16* __restrict__ wk, const u16* __restrict__ wv,
    u16* __restrict__ qo, u16* __restrict__ ko, u16* __restrict__ vto) {
  __shared__ u16 As[128 * 32];
  __shared__ u16 Bs[128 * 32];
  const int mb = blockIdx.x, yb = blockIdx.y;
  const u16* W;
  u16* C;
  int nb, ldc, mode;
  if (yb < 32)      { W = wq; C = qo;  nb = yb;      ldc = 4096; mode = 0; }
  else if (yb < 40) { W = wk; C = ko;  nb = yb - 32; ldc = 1024; mode = 0; }
  else              { W = wv; C = vto; nb = yb - 40; ldc = 0;    mode = 1; }

  f4 acc[4][4];
#pragma unroll
  for (int i = 0; i < 4; i++)
#pragma unroll
    for (int j = 0; j < 4; j++) acc[i][j] = (f4){0.f, 0.f, 0.f, 0.f};

  gemm_core(hidden, W, 4096, 4096, 4096, mb, nb, As, Bs, acc);

  const int tid = threadIdx.x, lane = tid & 63, wid = tid >> 6;
  const int l16 = lane & 15, quad = lane >> 4;
  const int wm = (wid >> 1) * 64, wn = (wid & 1) * 64;

  if (mode == 0) {
#pragma unroll
    for (int mt = 0; mt < 4; mt++)
#pragma unroll
      for (int nt = 0; nt < 4; nt++) {
        const int n = nb * 128 + wn + nt * 16 + l16;
        const int m0 = mb * 128 + wm + mt * 16 + quad * 4;
#pragma unroll
        for (int r = 0; r < 4; r++)
          C[(size_t)(m0 + r) * ldc + n] = f2b(acc[mt][nt][r]);
      }
  } else {
    // C rows are consecutive s at fixed d=n -> contiguous in vt[d][s]
#pragma unroll
    for (int mt = 0; mt < 4; mt++)
#pragma unroll
      for (int nt = 0; nt < 4; nt++) {
        const int n = nb * 128 + wn + nt * 16 + l16;
        const int m0 = mb * 128 + wm + mt * 16 + quad * 4;
        const int b_ = m0 >> 11, s0 = m0 & 2047;
        ushort4 pk;
        pk.x = f2b(acc[mt][nt][0]);
        pk.y = f2b(acc[mt][nt][1]);
        pk.z = f2b(acc[mt][nt][2]);
        pk.w = f2b(acc[mt][nt][3]);
        *(ushort4*)(vto + ((size_t)(b_ * 1024 + n) << 11) + s0) = pk;
      }
  }
}

// =====================================================================
// O projection: out(FP32) = attn(B*S x 4096, bf16) @ wo(4096 x 4096)^T.
// =====================================================================
__global__ __launch_bounds__(256) void gemm_o_kernel(
    const u16* __restrict__ A, const u16* __restrict__ W,
    float* __restrict__ C) {
  __shared__ u16 As[128 * 32];
  __shared__ u16 Bs[128 * 32];
  const int mb = blockIdx.x, nb = blockIdx.y;
  f4 acc[4][4];
#pragma unroll
  for (int i = 0; i < 4; i++)
#pragma unroll
    for (int j = 0; j < 4; j++) acc[i][j] = (f4){0.f, 0.f, 0.f, 0.f};

  gemm_core(A, W, 4096, 4096, 4096, mb, nb, As, Bs, acc);

  const int tid = threadIdx.x, lane = tid & 63, wid = tid >> 6;
  const int l16 = lane & 15, quad = lane >> 4;
  const int wm = (wid >> 1) * 64, wn = (wid & 1) * 64;
#pragma unroll
  for (int mt = 0; mt < 4; mt++)
#pragma unroll
    for (int nt = 0; nt < 4; nt++) {
      const int n = nb * 128 + wn + nt * 16 + l16;
      const int m0 = mb * 128 + wm + mt * 16 + quad * 4;
#pragma unroll
      for (int r = 0; r < 4; r++)
        C[(size_t)(m0 + r) * 4096 + n] = acc[mt][nt][r];
    }
}

// =====================================================================
// RoPE in-place on bf16 (B,S,nh,128). thread = 8 elems (4 even/odd pairs).
// =====================================================================
__global__ void rope_kernel(u16* __restrict__ x, const u16* __restrict__ cs,
                            const u16* __restrict__ sn, int shift, float scale,
                            int nthreads) {
  const int t = blockIdx.x * 256 + threadIdx.x;
  if (t >= nthreads) return;
  const size_t e = (size_t)t * 8;
  const int d = (int)(e & 127);
  const int s = (int)((e >> shift) & 2047);
  uint4 xv = *(const uint4*)(x + e);
  uint4 cv = *(const uint4*)(cs + (size_t)s * 128 + d);
  uint4 sv = *(const uint4*)(sn + (size_t)s * 128 + d);
  u32 xw[4] = {xv.x, xv.y, xv.z, xv.w};
  u32 cw[4] = {cv.x, cv.y, cv.z, cv.w};
  u32 sw[4] = {sv.x, sv.y, sv.z, sv.w};
  u32 ow[4];
#pragma unroll
  for (int i = 0; i < 4; i++) {
    float x0 = b2f(xw[i] & 0xffff), x1 = b2f(xw[i] >> 16);
    float c = b2f(cw[i] & 0xffff);   // cos[s,2i] == cos[s,2i+1]
    float si = b2f(sw[i] & 0xffff);
    float o0 = (x0 * c - x1 * si) * scale;
    float o1 = (x1 * c + x0 * si) * scale;
    ow[i] = (u32)f2b(o0) | ((u32)f2b(o1) << 16);
  }
  uint4 ov = {ow[0], ow[1], ow[2], ow[3]};
  *(uint4*)(x + e) = ov;
}

// =====================================================================
// Flash attention (causal, GQA). block = 64 queries of one head; 4 waves x
// 16 queries. NO K/V LDS STAGING: both MFMA B-operands are 16B-contiguous
// in global memory (K is [s][kv][d] d-contiguous; V is pre-transposed
// vt[d][s] s-contiguous), and the per-(b,kv) K/V working set is 1 MB =
// L2-resident. Each wave loads its own fragments straight from global
// (L1/L2-served), so there are ZERO __syncthreads in this kernel - waves
// free-run. Register-prefetch variants (rounds 2-3) spilled to scratch
// (WRITE_SIZE 33 MB -> 188/495 MB); this structure needs no long-lived
// staging registers at all. Only Ps (wave-private P transpose) uses LDS.
// Online softmax in exp2 domain with defer-max (T13, THR=8).
// =====================================================================
__global__ __launch_bounds__(256) void attn_kernel(
    const u16* __restrict__ q, const u16* __restrict__ k,
    const u16* __restrict__ vt, u16* __restrict__ attn) {
  __shared__ u16 Ps[4][16 * 72];  // per-wave [q][key], ld 72

  const int qblk = blockIdx.x, h = blockIdx.y, b = blockIdx.z;
  const int kv = h >> 2;
  const int tid = threadIdx.x, lane = tid & 63, wid = tid >> 6;
  const int l16 = lane & 15, quad = lane >> 4;

  // register-resident Q A-frags (16 queries of this wave)
  const u16* qp =
      q + ((size_t)(b * 2048 + qblk * 64 + wid * 16 + l16) * 32 + h) * 128;
  bf8 aq[4];
#pragma unroll
  for (int ds = 0; ds < 4; ds++)
    aq[ds] = *(const bf8*)(qp + ds * 32 + quad * 8);

  f4 accO[8];
#pragma unroll
  for (int i = 0; i < 8; i++) accO[i] = (f4){0.f, 0.f, 0.f, 0.f};
  float mrow[4] = {-1e30f, -1e30f, -1e30f, -1e30f};
  float lrow[4] = {0.f, 0.f, 0.f, 0.f};

  // per-lane fragment base pointers (B-operands read directly from global)
  // K frag elem: kp + (key0 + nt*16 + l16)*1024 + ds*32 + quad*8
  const u16* kfrag = k + ((size_t)(b * 2048 + l16) * 8 + kv) * 128 + quad * 8;
  // V frag elem: vp + (nt*16 + l16)*2048 + key0 + ks*32 + quad*8
  const u16* vfrag =
      vt + ((size_t)(b * 8 + kv) * 128 + l16) * 2048 + quad * 8;

  const int qg = qblk * 64 + wid * 16 + quad * 4;  // + r = this lane's rows

  for (int kt = 0; kt <= qblk; kt++) {
    const int key0 = kt * 64;

    // ---- scores: 16q x 64k per wave; K frags straight from global ----
    f4 sc[4];
#pragma unroll
    for (int nt = 0; nt < 4; nt++) {
      sc[nt] = (f4){0.f, 0.f, 0.f, 0.f};
#pragma unroll
      for (int ds = 0; ds < 4; ds++) {
        bf8 bk = *(const bf8*)(kfrag + (size_t)(key0 + nt * 16) * 1024 +
                               ds * 32);
        sc[nt] = mfma16(aq[ds], bk, sc[nt]);
      }
    }

    // ---- causal mask + online softmax (rows = quad*4+r, cols via l16) ----
    u16 pbits[4][4];
#pragma unroll
    for (int r = 0; r < 4; r++) {
      float mx = -1e30f;
#pragma unroll
      for (int nt = 0; nt < 4; nt++) {
        const int keyg = key0 + nt * 16 + l16;
        if (keyg > qg + r) sc[nt][r] = -1e30f;
        mx = fmaxf(mx, sc[nt][r]);
      }
#pragma unroll
      for (int off = 1; off < 16; off <<= 1)
        mx = fmaxf(mx, __shfl_xor(mx, off, 64));
      // defer-max (T13): only rescale when tile max grows by > 8 (exp2 dom)
      if (mx - mrow[r] > 8.f) {
        const float mn = fmaxf(mrow[r], mx);
        const float alpha = exp2f(mrow[r] - mn);
        mrow[r] = mn;
        lrow[r] *= alpha;
#pragma unroll
        for (int nt = 0; nt < 8; nt++) accO[nt][r] *= alpha;
      }
      const float mr = mrow[r];
      float ps = 0.f;
#pragma unroll
      for (int nt = 0; nt < 4; nt++) {
        const float p = exp2f(sc[nt][r] - mr);
        ps += p;
        pbits[nt][r] = f2b(p);
      }
#pragma unroll
      for (int off = 1; off < 16; off <<= 1) ps += __shfl_xor(ps, off, 64);
      lrow[r] += ps;
    }

    // ---- P -> LDS (A-operand layout); wave-private, no barrier needed ----
#pragma unroll
    for (int nt = 0; nt < 4; nt++)
#pragma unroll
      for (int r = 0; r < 4; r++)
        Ps[wid][(quad * 4 + r) * 72 + nt * 16 + l16] = pbits[nt][r];

    // ---- PV: accO[16q x 128d] += P[16x64] * V[64x128]; V from global ----
#pragma unroll
    for (int ks = 0; ks < 2; ks++) {
      bf8 ap = *(const bf8*)(&Ps[wid][l16 * 72 + ks * 32 + quad * 8]);
#pragma unroll
      for (int nt = 0; nt < 8; nt++) {
        bf8 bv = *(const bf8*)(vfrag + (size_t)(nt * 16) * 2048 + key0 +
                               ks * 32);
        accO[nt] = mfma16(ap, bv, accO[nt]);
      }
    }
  }

  // ---- epilogue: attn[b][s][h][d] bf16 ----
  float inv[4];
#pragma unroll
  for (int r = 0; r < 4; r++) inv[r] = 1.0f / lrow[r];
#pragma unroll
  for (int nt = 0; nt < 8; nt++)
#pragma unroll
    for (int r = 0; r < 4; r++) {
      const int s = qblk * 64 + wid * 16 + quad * 4 + r;
      const int dcol = nt * 16 + l16;
      attn[((size_t)(b * 2048 + s) * 32 + h) * 128 + dcol] =
          f2b(accO[nt][r] * inv[r]);
    }
}

// =====================================================================
extern "C" void kernel_launch(void* const* d_in, const int* in_sizes, int n_in,
                              void* d_out, int out_size, void* d_ws,
                              size_t ws_size, hipStream_t stream) {
  const u16* hidden = (const u16*)d_in[0];
  const u16* cosp = (const u16*)d_in[1];
  const u16* sinp = (const u16*)d_in[2];
  const u16* wq = (const u16*)d_in[3];
  const u16* wk = (const u16*)d_in[4];
  const u16* wv = (const u16*)d_in[5];
  const u16* wo = (const u16*)d_in[6];
  const u32* probe = (const u32*)d_in[1];  // cos[0] == 1.0
  float* out = (float*)d_out;              // fp32 output

  char* ws = (char*)d_ws;
  // hidden_n region is reused as attnb after gemm_qkv completes.
  u16* hidden_n = (u16*)(ws);                    // 32 MiB
  u16* attnb    = (u16*)(ws);                    // 32 MiB (alias, later)
  u16* qb       = (u16*)(ws + 33554432);         // 32 MiB
  u16* kb       = (u16*)(ws + 67108864);         //  8 MiB
  u16* vtb      = (u16*)(ws + 75497472);         //  8 MiB
  u16* wq_n     = (u16*)(ws + 83886080);         // 32 MiB
  u16* wk_n     = (u16*)(ws + 117440512);        //  8 MiB
  u16* wv_n     = (u16*)(ws + 125829120);        //  8 MiB
  u16* wo_n     = (u16*)(ws + 134217728);        // 32 MiB
  u16* cos_n    = (u16*)(ws + 167772160);        // 0.5 MiB
  u16* sin_n    = (u16*)(ws + 168296448);        // 0.5 MiB

  dim3 blk(256);
  // normalize all inputs to bf16 (runtime dtype detection via probe)
  convert_kernel<<<dim3(8192), blk, 0, stream>>>(hidden, hidden_n, probe,
                                                 2097152);
  convert_kernel<<<dim3(8192), blk, 0, stream>>>(wq, wq_n, probe, 2097152);
  convert_kernel<<<dim3(2048), blk, 0, stream>>>(wk, wk_n, probe, 524288);
  convert_kernel<<<dim3(2048), blk, 0, stream>>>(wv, wv_n, probe, 524288);
  convert_kernel<<<dim3(8192), blk, 0, stream>>>(wo, wo_n, probe, 2097152);
  convert_kernel<<<dim3(128), blk, 0, stream>>>(cosp, cos_n, probe, 32768);
  convert_kernel<<<dim3(128), blk, 0, stream>>>(sinp, sin_n, probe, 32768);

  gemm_qkv_kernel<<<dim3(32, 48), blk, 0, stream>>>(hidden_n, wq_n, wk_n, wv_n,
                                                    qb, kb, vtb);
  rope_kernel<<<dim3(8192), blk, 0, stream>>>(qb, cos_n, sin_n, 12, QSCALE,
                                              2097152);
  rope_kernel<<<dim3(2048), blk, 0, stream>>>(kb, cos_n, sin_n, 10, 1.0f,
                                              524288);
  attn_kernel<<<dim3(32, 32, 2), blk, 0, stream>>>(qb, kb, vtb, attnb);
  gemm_o_kernel<<<dim3(32, 32), blk, 0, stream>>>(attnb, wo_n, out);
}

// Round 5
// 1177.934 us; speedup vs baseline: 1.4065x; 1.4065x over previous
//
#include <hip/hip_runtime.h>

typedef unsigned short u16;
typedef unsigned int u32;
using bf8 = __attribute__((ext_vector_type(8))) short;  // 8 bf16 (4 VGPRs)
using f4  = __attribute__((ext_vector_type(4))) float;  // MFMA acc

#define DEV __device__ __forceinline__

// B=2, S=2048, HID=4096, H=32, KV=8, D=128, G=4
// q scale folded into rope: (1/sqrt(128)) * log2(e)  -> softmax in exp2 domain
#define QSCALE (0.08838834764831845f * 1.4426950408889634f)

DEV u16 f2b(float f) {            // RNE fp32 -> bf16 bits
  u32 u = __float_as_uint(f);
  u32 r = u + 0x7fff + ((u >> 16) & 1);
  return (u16)(r >> 16);
}
DEV u32 f2b_u(u32 u) {            // RNE from fp32 bits
  return (u + 0x7fff + ((u >> 16) & 1)) >> 16;
}
DEV float b2f(u32 bits) { return __uint_as_float(bits << 16); }

#define GLOAD16(g, l)                                                          \
  __builtin_amdgcn_global_load_lds((__attribute__((address_space(1))) u32*)(g),\
                                   (__attribute__((address_space(3))) u32*)(l),\
                                   16, 0, 0)

DEV f4 mfma16(bf8 a, bf8 b, f4 c) {
  return __builtin_amdgcn_mfma_f32_16x16x32_bf16(a, b, c, 0, 0, 0);
}

// =====================================================================
// Input normalizer: copies src -> dst as bf16. Detects src dtype at
// runtime from probe[0] (cos[0]==1.0: fp32 -> 0x3F800000, bf16 -> 0x3F803F80).
// n8 = element count / 8.
// =====================================================================
__global__ __launch_bounds__(256) void convert_kernel(
    const u16* __restrict__ src, u16* __restrict__ dst,
    const u32* __restrict__ probe, int n8) {
  const int t = blockIdx.x * 256 + threadIdx.x;
  if (t >= n8) return;
  const bool isf32 = (probe[0] == 0x3F800000u);
  const uint4* s4 = (const uint4*)src;
  uint4* d4 = (uint4*)dst;
  if (!isf32) {
    d4[t] = s4[t];
    return;
  }
  uint4 a = s4[2 * t];
  uint4 b = s4[2 * t + 1];
  uint4 o;
  o.x = f2b_u(a.x) | (f2b_u(a.y) << 16);
  o.y = f2b_u(a.z) | (f2b_u(a.w) << 16);
  o.z = f2b_u(b.x) | (f2b_u(b.y) << 16);
  o.w = f2b_u(b.z) | (f2b_u(b.w) << 16);
  d4[t] = o;
}

// =====================================================================
// GEMM core: C[128x128 tile] = A(M x K, rm) * W(N x K, rm)^T  (m97 pattern)
// =====================================================================
DEV void gemm_core(const u16* __restrict__ A, const u16* __restrict__ W,
                   int lda, int ldw, int K, int mb, int nb,
                   u16* As, u16* Bs, f4 (&acc)[4][4]) {
  const int tid = threadIdx.x;
  const int lane = tid & 63;
  const int wid = tid >> 6;
  const int l16 = lane & 15;
  const int quad = lane >> 4;
  const int wm = (wid >> 1) * 64;
  const int wn = (wid & 1) * 64;

  const int c0 = wid * 2;
  const int rowA0 = c0 * 16 + (lane >> 2);
  const int colb = (lane & 3) * 16;

  const char* gA = (const char*)(A + (size_t)(mb * 128 + rowA0) * lda) + colb;
  const char* gB = (const char*)(W + (size_t)(nb * 128 + rowA0) * ldw) + colb;
  char* lA = (char*)As + c0 * 1024;
  char* lB = (char*)Bs + c0 * 1024;
  const size_t strideA = (size_t)lda * 32;
  const size_t strideB = (size_t)ldw * 32;

  for (int k0 = 0; k0 < K; k0 += 32) {
    __syncthreads();
    GLOAD16(gA + (size_t)k0 * 2, lA);
    GLOAD16(gA + (size_t)k0 * 2 + strideA, lA + 1024);
    GLOAD16(gB + (size_t)k0 * 2, lB);
    GLOAD16(gB + (size_t)k0 * 2 + strideB, lB + 1024);
    __syncthreads();

    bf8 af[4], bw[4];
#pragma unroll
    for (int t = 0; t < 4; t++) {
      af[t] = *(const bf8*)(As + (wm + t * 16 + l16) * 32 + quad * 8);
      bw[t] = *(const bf8*)(Bs + (wn + t * 16 + l16) * 32 + quad * 8);
    }
#pragma unroll
    for (int mt = 0; mt < 4; mt++)
#pragma unroll
      for (int nt = 0; nt < 4; nt++)
        acc[mt][nt] = mfma16(af[mt], bw[nt], acc[mt][nt]);
  }
}

// =====================================================================
// Fused QKV projection. grid (32, 48): y<32 -> Q, y<40 -> K, else V.
// V written transposed: vt[(b*KV+kv)*D + d][s].
// =====================================================================
__global__ __launch_bounds__(256) void gemm_qkv_kernel(
    const u16* __restrict__ hidden, const u16* __restrict__ wq,
    const u16* __restrict__ wk, const u16* __restrict__ wv,
    u16* __restrict__ qo, u16* __restrict__ ko, u16* __restrict__ vto) {
  __shared__ u16 As[128 * 32];
  __shared__ u16 Bs[128 * 32];
  const int mb = blockIdx.x, yb = blockIdx.y;
  const u16* W;
  u16* C;
  int nb, ldc, mode;
  if (yb < 32)      { W = wq; C = qo;  nb = yb;      ldc = 4096; mode = 0; }
  else if (yb < 40) { W = wk; C = ko;  nb = yb - 32; ldc = 1024; mode = 0; }
  else              { W = wv; C = vto; nb = yb - 40; ldc = 0;    mode = 1; }

  f4 acc[4][4];
#pragma unroll
  for (int i = 0; i < 4; i++)
#pragma unroll
    for (int j = 0; j < 4; j++) acc[i][j] = (f4){0.f, 0.f, 0.f, 0.f};

  gemm_core(hidden, W, 4096, 4096, 4096, mb, nb, As, Bs, acc);

  const int tid = threadIdx.x, lane = tid & 63, wid = tid >> 6;
  const int l16 = lane & 15, quad = lane >> 4;
  const int wm = (wid >> 1) * 64, wn = (wid & 1) * 64;

  if (mode == 0) {
#pragma unroll
    for (int mt = 0; mt < 4; mt++)
#pragma unroll
      for (int nt = 0; nt < 4; nt++) {
        const int n = nb * 128 + wn + nt * 16 + l16;
        const int m0 = mb * 128 + wm + mt * 16 + quad * 4;
#pragma unroll
        for (int r = 0; r < 4; r++)
          C[(size_t)(m0 + r) * ldc + n] = f2b(acc[mt][nt][r]);
      }
  } else {
    // C rows are consecutive s at fixed d=n -> contiguous in vt[d][s]
#pragma unroll
    for (int mt = 0; mt < 4; mt++)
#pragma unroll
      for (int nt = 0; nt < 4; nt++) {
        const int n = nb * 128 + wn + nt * 16 + l16;
        const int m0 = mb * 128 + wm + mt * 16 + quad * 4;
        const int b_ = m0 >> 11, s0 = m0 & 2047;
        ushort4 pk;
        pk.x = f2b(acc[mt][nt][0]);
        pk.y = f2b(acc[mt][nt][1]);
        pk.z = f2b(acc[mt][nt][2]);
        pk.w = f2b(acc[mt][nt][3]);
        *(ushort4*)(vto + ((size_t)(b_ * 1024 + n) << 11) + s0) = pk;
      }
  }
}

// =====================================================================
// O projection: out(FP32) = attn(B*S x 4096, bf16) @ wo(4096 x 4096)^T.
// =====================================================================
__global__ __launch_bounds__(256) void gemm_o_kernel(
    const u16* __restrict__ A, const u16* __restrict__ W,
    float* __restrict__ C) {
  __shared__ u16 As[128 * 32];
  __shared__ u16 Bs[128 * 32];
  const int mb = blockIdx.x, nb = blockIdx.y;
  f4 acc[4][4];
#pragma unroll
  for (int i = 0; i < 4; i++)
#pragma unroll
    for (int j = 0; j < 4; j++) acc[i][j] = (f4){0.f, 0.f, 0.f, 0.f};

  gemm_core(A, W, 4096, 4096, 4096, mb, nb, As, Bs, acc);

  const int tid = threadIdx.x, lane = tid & 63, wid = tid >> 6;
  const int l16 = lane & 15, quad = lane >> 4;
  const int wm = (wid >> 1) * 64, wn = (wid & 1) * 64;
#pragma unroll
  for (int mt = 0; mt < 4; mt++)
#pragma unroll
    for (int nt = 0; nt < 4; nt++) {
      const int n = nb * 128 + wn + nt * 16 + l16;
      const int m0 = mb * 128 + wm + mt * 16 + quad * 4;
#pragma unroll
      for (int r = 0; r < 4; r++)
        C[(size_t)(m0 + r) * 4096 + n] = acc[mt][nt][r];
    }
}

// =====================================================================
// RoPE in-place on bf16 (B,S,nh,128). thread = 8 elems (4 even/odd pairs).
// =====================================================================
__global__ void rope_kernel(u16* __restrict__ x, const u16* __restrict__ cs,
                            const u16* __restrict__ sn, int shift, float scale,
                            int nthreads) {
  const int t = blockIdx.x * 256 + threadIdx.x;
  if (t >= nthreads) return;
  const size_t e = (size_t)t * 8;
  const int d = (int)(e & 127);
  const int s = (int)((e >> shift) & 2047);
  uint4 xv = *(const uint4*)(x + e);
  uint4 cv = *(const uint4*)(cs + (size_t)s * 128 + d);
  uint4 sv = *(const uint4*)(sn + (size_t)s * 128 + d);
  u32 xw[4] = {xv.x, xv.y, xv.z, xv.w};
  u32 cw[4] = {cv.x, cv.y, cv.z, cv.w};
  u32 sw[4] = {sv.x, sv.y, sv.z, sv.w};
  u32 ow[4];
#pragma unroll
  for (int i = 0; i < 4; i++) {
    float x0 = b2f(xw[i] & 0xffff), x1 = b2f(xw[i] >> 16);
    float c = b2f(cw[i] & 0xffff);   // cos[s,2i] == cos[s,2i+1]
    float si = b2f(sw[i] & 0xffff);
    float o0 = (x0 * c - x1 * si) * scale;
    float o1 = (x1 * c + x0 * si) * scale;
    ow[i] = (u32)f2b(o0) | ((u32)f2b(o1) << 16);
  }
  uint4 ov = {ow[0], ow[1], ow[2], ow[3]};
  *(uint4*)(x + e) = ov;
}

// =====================================================================
// Flash attention (causal, GQA). block = 64 queries of one head; 4 waves x
// 16 queries. Round-0 staging structure (LDS-staged K/V, fused load->write
// between barriers; reg-prefetch and direct-global variants both measured
// slower). SWAPPED QK^T (T12 mechanism): compute mfma(K,Q) so the output is
// S[key][query] and each lane holds all 16 of its scores for ONE query
// (query = l16). The softmax reduce is then 15 in-lane fmax + 2 shfl_xor
// (quad fold) instead of 4 rows x 4-step shfl chains: 4 shuffles/tile-wave
// instead of 32 (the round-0 bottleneck: ~1000 cyc of chained shfl latency
// vs 160 cyc of MFMA). m/l are per-lane scalars; alpha/inv redistributed to
// the acc row layout (query = quad*4+r) by 4 shfls, rescale gated by a
// wave-uniform ballot (defer-max T13, THR=8 in exp2 domain). PV and the
// epilogue are unchanged from round 0. 2 barriers/tile (Ps is wave-private;
// removal validated rounds 2-4).
// =====================================================================
__global__ __launch_bounds__(256) void attn_kernel(
    const u16* __restrict__ q, const u16* __restrict__ k,
    const u16* __restrict__ vt, u16* __restrict__ attn) {
  __shared__ u16 Ks[64 * 136];    // [key][d], ld 136
  __shared__ u16 Vt[128 * 72];    // [d][key], ld 72
  __shared__ u16 Ps[4][16 * 72];  // per-wave [q][key], ld 72

  const int qblk = blockIdx.x, h = blockIdx.y, b = blockIdx.z;
  const int kv = h >> 2;
  const int tid = threadIdx.x, lane = tid & 63, wid = tid >> 6;
  const int l16 = lane & 15, quad = lane >> 4;

  // register-resident Q A-frags (16 queries of this wave)
  const u16* qp =
      q + ((size_t)(b * 2048 + qblk * 64 + wid * 16 + l16) * 32 + h) * 128;
  bf8 aq[4];
#pragma unroll
  for (int ds = 0; ds < 4; ds++)
    aq[ds] = *(const bf8*)(qp + ds * 32 + quad * 8);

  f4 accO[8];
#pragma unroll
  for (int i = 0; i < 8; i++) accO[i] = (f4){0.f, 0.f, 0.f, 0.f};
  float m = -1e30f;   // running max of query l16 (uniform across quads)
  float l = 0.f;      // running denom of query l16

  const u16* kp = k + ((size_t)(b * 2048) * 8 + kv) * 128;   // key stride 1024
  const u16* vp = vt + (size_t)(b * 8 + kv) * 128 * 2048;    // d stride 2048

  const int qglob = qblk * 64 + wid * 16 + l16;  // this lane's query index

  for (int kt = 0; kt <= qblk; kt++) {
    const int key0 = kt * 64;
    __syncthreads();
    // stage K tile [64][128]: 4 reps x 256 threads x 8 u16
#pragma unroll
    for (int rep = 0; rep < 4; rep++) {
      const int e = rep * 2048 + tid * 8;
      const int row = e >> 7, col = e & 127;
      *(uint4*)(Ks + row * 136 + col) =
          *(const uint4*)(kp + (size_t)(key0 + row) * 1024 + col);
    }
    // stage Vt tile [128][64]
#pragma unroll
    for (int rep = 0; rep < 4; rep++) {
      const int e = rep * 2048 + tid * 8;
      const int row = e >> 6, col = e & 63;
      *(uint4*)(Vt + row * 72 + col) =
          *(const uint4*)(vp + (size_t)row * 2048 + key0 + col);
    }
    __syncthreads();

    // ---- scores (swapped): sc[nt][r] = S[key0+nt*16+quad*4+r][q=l16] ----
    f4 sc[4];
#pragma unroll
    for (int nt = 0; nt < 4; nt++) {
      sc[nt] = (f4){0.f, 0.f, 0.f, 0.f};
      const int krow = nt * 16 + l16;
#pragma unroll
      for (int ds = 0; ds < 4; ds++) {
        bf8 bk = *(const bf8*)(Ks + krow * 136 + ds * 32 + quad * 8);
        sc[nt] = mfma16(bk, aq[ds], sc[nt]);  // swapped operands
      }
    }

    // ---- causal mask (diagonal tile only; wave-uniform branch) ----
    if (kt == qblk) {
#pragma unroll
      for (int nt = 0; nt < 4; nt++)
#pragma unroll
        for (int r = 0; r < 4; r++)
          if (key0 + nt * 16 + quad * 4 + r > qglob) sc[nt][r] = -1e30f;
    }

    // ---- online softmax, query-major (16 scores in-lane + quad fold) ----
    float mx = -1e30f;
#pragma unroll
    for (int nt = 0; nt < 4; nt++) {
      const float a = fmaxf(fmaxf(sc[nt][0], sc[nt][1]),
                            fmaxf(sc[nt][2], sc[nt][3]));
      mx = fmaxf(mx, a);
    }
    mx = fmaxf(mx, __shfl_xor(mx, 16, 64));
    mx = fmaxf(mx, __shfl_xor(mx, 32, 64));

    // defer-max (T13): only rescale when tile max grows by > 8 (exp2 dom)
    const bool grow = (mx - m > 8.f);
    float alpha = 1.f;
    if (grow) {
      alpha = exp2f(m - mx);
      m = mx;
      l *= alpha;
    }
    if (__ballot(grow)) {  // wave-uniform skip of the accO rescale
#pragma unroll
      for (int r = 0; r < 4; r++) {
        const float ar = __shfl(alpha, (lane & 48) | (quad * 4 + r), 64);
#pragma unroll
        for (int nt = 0; nt < 8; nt++) accO[nt][r] *= ar;
      }
    }

    u16 pbits[4][4];
    float ps = 0.f;
#pragma unroll
    for (int nt = 0; nt < 4; nt++)
#pragma unroll
      for (int r = 0; r < 4; r++) {
        const float p = exp2f(sc[nt][r] - m);
        ps += p;
        pbits[nt][r] = f2b(p);
      }
    ps += __shfl_xor(ps, 16, 64);
    ps += __shfl_xor(ps, 32, 64);
    l += ps;

    // ---- P -> LDS [q=l16][key]; r=0..3 are consecutive keys -> b64 ----
#pragma unroll
    for (int nt = 0; nt < 4; nt++) {
      ushort4 pk;
      pk.x = pbits[nt][0];
      pk.y = pbits[nt][1];
      pk.z = pbits[nt][2];
      pk.w = pbits[nt][3];
      *(ushort4*)(&Ps[wid][l16 * 72 + nt * 16 + quad * 4]) = pk;
    }

    // ---- PV: accO[16q x 128d] += P[16x64] * V[64x128] ----
#pragma unroll
    for (int ks = 0; ks < 2; ks++) {
      bf8 ap = *(const bf8*)(&Ps[wid][l16 * 72 + ks * 32 + quad * 8]);
#pragma unroll
      for (int nt = 0; nt < 8; nt++) {
        bf8 bv = *(const bf8*)(Vt + (nt * 16 + l16) * 72 + ks * 32 + quad * 8);
        accO[nt] = mfma16(ap, bv, accO[nt]);
      }
    }
  }

  // ---- epilogue: attn[b][s][h][d] bf16 ----
  const float invq = 1.0f / l;
  float inv[4];
#pragma unroll
  for (int r = 0; r < 4; r++)
    inv[r] = __shfl(invq, (lane & 48) | (quad * 4 + r), 64);
#pragma unroll
  for (int nt = 0; nt < 8; nt++)
#pragma unroll
    for (int r = 0; r < 4; r++) {
      const int s = qblk * 64 + wid * 16 + quad * 4 + r;
      const int dcol = nt * 16 + l16;
      attn[((size_t)(b * 2048 + s) * 32 + h) * 128 + dcol] =
          f2b(accO[nt][r] * inv[r]);
    }
}

// =====================================================================
extern "C" void kernel_launch(void* const* d_in, const int* in_sizes, int n_in,
                              void* d_out, int out_size, void* d_ws,
                              size_t ws_size, hipStream_t stream) {
  const u16* hidden = (const u16*)d_in[0];
  const u16* cosp = (const u16*)d_in[1];
  const u16* sinp = (const u16*)d_in[2];
  const u16* wq = (const u16*)d_in[3];
  const u16* wk = (const u16*)d_in[4];
  const u16* wv = (const u16*)d_in[5];
  const u16* wo = (const u16*)d_in[6];
  const u32* probe = (const u32*)d_in[1];  // cos[0] == 1.0
  float* out = (float*)d_out;              // fp32 output

  char* ws = (char*)d_ws;
  // hidden_n region is reused as attnb after gemm_qkv completes.
  u16* hidden_n = (u16*)(ws);                    // 32 MiB
  u16* attnb    = (u16*)(ws);                    // 32 MiB (alias, later)
  u16* qb       = (u16*)(ws + 33554432);         // 32 MiB
  u16* kb       = (u16*)(ws + 67108864);         //  8 MiB
  u16* vtb      = (u16*)(ws + 75497472);         //  8 MiB
  u16* wq_n     = (u16*)(ws + 83886080);         // 32 MiB
  u16* wk_n     = (u16*)(ws + 117440512);        //  8 MiB
  u16* wv_n     = (u16*)(ws + 125829120);        //  8 MiB
  u16* wo_n     = (u16*)(ws + 134217728);        // 32 MiB
  u16* cos_n    = (u16*)(ws + 167772160);        // 0.5 MiB
  u16* sin_n    = (u16*)(ws + 168296448);        // 0.5 MiB

  dim3 blk(256);
  // normalize all inputs to bf16 (runtime dtype detection via probe)
  convert_kernel<<<dim3(8192), blk, 0, stream>>>(hidden, hidden_n, probe,
                                                 2097152);
  convert_kernel<<<dim3(8192), blk, 0, stream>>>(wq, wq_n, probe, 2097152);
  convert_kernel<<<dim3(2048), blk, 0, stream>>>(wk, wk_n, probe, 524288);
  convert_kernel<<<dim3(2048), blk, 0, stream>>>(wv, wv_n, probe, 524288);
  convert_kernel<<<dim3(8192), blk, 0, stream>>>(wo, wo_n, probe, 2097152);
  convert_kernel<<<dim3(128), blk, 0, stream>>>(cosp, cos_n, probe, 32768);
  convert_kernel<<<dim3(128), blk, 0, stream>>>(sinp, sin_n, probe, 32768);

  gemm_qkv_kernel<<<dim3(32, 48), blk, 0, stream>>>(hidden_n, wq_n, wk_n, wv_n,
                                                    qb, kb, vtb);
  rope_kernel<<<dim3(8192), blk, 0, stream>>>(qb, cos_n, sin_n, 12, QSCALE,
                                              2097152);
  rope_kernel<<<dim3(2048), blk, 0, stream>>>(kb, cos_n, sin_n, 10, 1.0f,
                                              524288);
  attn_kernel<<<dim3(32, 32, 2), blk, 0, stream>>>(qb, kb, vtb, attnb);
  gemm_o_kernel<<<dim3(32, 32), blk, 0, stream>>>(attnb, wo_n, out);
}

// Round 6
// 1006.332 us; speedup vs baseline: 1.6464x; 1.1705x over previous
//
#include <hip/hip_runtime.h>

typedef unsigned short u16;
typedef unsigned int u32;
using bf8 = __attribute__((ext_vector_type(8))) short;  // 8 bf16 (4 VGPRs)
using f4  = __attribute__((ext_vector_type(4))) float;  // MFMA acc

#define DEV __device__ __forceinline__

// B=2, S=2048, HID=4096, H=32, KV=8, D=128, G=4
// q scale folded into rope: (1/sqrt(128)) * log2(e)  -> softmax in exp2 domain
#define QSCALE (0.08838834764831845f * 1.4426950408889634f)

DEV u16 f2b(float f) {            // RNE fp32 -> bf16 bits
  u32 u = __float_as_uint(f);
  u32 r = u + 0x7fff + ((u >> 16) & 1);
  return (u16)(r >> 16);
}
DEV u32 f2b_u(u32 u) {            // RNE from fp32 bits
  return (u + 0x7fff + ((u >> 16) & 1)) >> 16;
}
DEV float b2f(u32 bits) { return __uint_as_float(bits << 16); }

#define GLOAD16(g, l)                                                          \
  __builtin_amdgcn_global_load_lds((__attribute__((address_space(1))) u32*)(g),\
                                   (__attribute__((address_space(3))) u32*)(l),\
                                   16, 0, 0)

DEV f4 mfma16(bf8 a, bf8 b, f4 c) {
  return __builtin_amdgcn_mfma_f32_16x16x32_bf16(a, b, c, 0, 0, 0);
}

// =====================================================================
// Input normalizer: copies src -> dst as bf16. Detects src dtype at
// runtime from probe[0] (cos[0]==1.0: fp32 -> 0x3F800000, bf16 -> 0x3F803F80).
// n8 = element count / 8.
// =====================================================================
__global__ __launch_bounds__(256) void convert_kernel(
    const u16* __restrict__ src, u16* __restrict__ dst,
    const u32* __restrict__ probe, int n8) {
  const int t = blockIdx.x * 256 + threadIdx.x;
  if (t >= n8) return;
  const bool isf32 = (probe[0] == 0x3F800000u);
  const uint4* s4 = (const uint4*)src;
  uint4* d4 = (uint4*)dst;
  if (!isf32) {
    d4[t] = s4[t];
    return;
  }
  uint4 a = s4[2 * t];
  uint4 b = s4[2 * t + 1];
  uint4 o;
  o.x = f2b_u(a.x) | (f2b_u(a.y) << 16);
  o.y = f2b_u(a.z) | (f2b_u(a.w) << 16);
  o.z = f2b_u(b.x) | (f2b_u(b.y) << 16);
  o.w = f2b_u(b.z) | (f2b_u(b.w) << 16);
  d4[t] = o;
}

// =====================================================================
// GEMM core: C[128x128 tile] = A(M x K, rm) * W(N x K, rm)^T  (m97 pattern)
// =====================================================================
DEV void gemm_core(const u16* __restrict__ A, const u16* __restrict__ W,
                   int lda, int ldw, int K, int mb, int nb,
                   u16* As, u16* Bs, f4 (&acc)[4][4]) {
  const int tid = threadIdx.x;
  const int lane = tid & 63;
  const int wid = tid >> 6;
  const int l16 = lane & 15;
  const int quad = lane >> 4;
  const int wm = (wid >> 1) * 64;
  const int wn = (wid & 1) * 64;

  const int c0 = wid * 2;
  const int rowA0 = c0 * 16 + (lane >> 2);
  const int colb = (lane & 3) * 16;

  const char* gA = (const char*)(A + (size_t)(mb * 128 + rowA0) * lda) + colb;
  const char* gB = (const char*)(W + (size_t)(nb * 128 + rowA0) * ldw) + colb;
  char* lA = (char*)As + c0 * 1024;
  char* lB = (char*)Bs + c0 * 1024;
  const size_t strideA = (size_t)lda * 32;
  const size_t strideB = (size_t)ldw * 32;

  for (int k0 = 0; k0 < K; k0 += 32) {
    __syncthreads();
    GLOAD16(gA + (size_t)k0 * 2, lA);
    GLOAD16(gA + (size_t)k0 * 2 + strideA, lA + 1024);
    GLOAD16(gB + (size_t)k0 * 2, lB);
    GLOAD16(gB + (size_t)k0 * 2 + strideB, lB + 1024);
    __syncthreads();

    bf8 af[4], bw[4];
#pragma unroll
    for (int t = 0; t < 4; t++) {
      af[t] = *(const bf8*)(As + (wm + t * 16 + l16) * 32 + quad * 8);
      bw[t] = *(const bf8*)(Bs + (wn + t * 16 + l16) * 32 + quad * 8);
    }
#pragma unroll
    for (int mt = 0; mt < 4; mt++)
#pragma unroll
      for (int nt = 0; nt < 4; nt++)
        acc[mt][nt] = mfma16(af[mt], bw[nt], acc[mt][nt]);
  }
}

// =====================================================================
// Fused QKV projection. grid (32, 48): y<32 -> Q, y<40 -> K, else V.
// V written transposed: vt[(b*KV+kv)*D + d][s].
// =====================================================================
__global__ __launch_bounds__(256) void gemm_qkv_kernel(
    const u16* __restrict__ hidden, const u16* __restrict__ wq,
    const u16* __restrict__ wk, const u16* __restrict__ wv,
    u16* __restrict__ qo, u16* __restrict__ ko, u16* __restrict__ vto) {
  __shared__ u16 As[128 * 32];
  __shared__ u16 Bs[128 * 32];
  const int mb = blockIdx.x, yb = blockIdx.y;
  const u16* W;
  u16* C;
  int nb, ldc, mode;
  if (yb < 32)      { W = wq; C = qo;  nb = yb;      ldc = 4096; mode = 0; }
  else if (yb < 40) { W = wk; C = ko;  nb = yb - 32; ldc = 1024; mode = 0; }
  else              { W = wv; C = vto; nb = yb - 40; ldc = 0;    mode = 1; }

  f4 acc[4][4];
#pragma unroll
  for (int i = 0; i < 4; i++)
#pragma unroll
    for (int j = 0; j < 4; j++) acc[i][j] = (f4){0.f, 0.f, 0.f, 0.f};

  gemm_core(hidden, W, 4096, 4096, 4096, mb, nb, As, Bs, acc);

  const int tid = threadIdx.x, lane = tid & 63, wid = tid >> 6;
  const int l16 = lane & 15, quad = lane >> 4;
  const int wm = (wid >> 1) * 64, wn = (wid & 1) * 64;

  if (mode == 0) {
#pragma unroll
    for (int mt = 0; mt < 4; mt++)
#pragma unroll
      for (int nt = 0; nt < 4; nt++) {
        const int n = nb * 128 + wn + nt * 16 + l16;
        const int m0 = mb * 128 + wm + mt * 16 + quad * 4;
#pragma unroll
        for (int r = 0; r < 4; r++)
          C[(size_t)(m0 + r) * ldc + n] = f2b(acc[mt][nt][r]);
      }
  } else {
    // C rows are consecutive s at fixed d=n -> contiguous in vt[d][s]
#pragma unroll
    for (int mt = 0; mt < 4; mt++)
#pragma unroll
      for (int nt = 0; nt < 4; nt++) {
        const int n = nb * 128 + wn + nt * 16 + l16;
        const int m0 = mb * 128 + wm + mt * 16 + quad * 4;
        const int b_ = m0 >> 11, s0 = m0 & 2047;
        ushort4 pk;
        pk.x = f2b(acc[mt][nt][0]);
        pk.y = f2b(acc[mt][nt][1]);
        pk.z = f2b(acc[mt][nt][2]);
        pk.w = f2b(acc[mt][nt][3]);
        *(ushort4*)(vto + ((size_t)(b_ * 1024 + n) << 11) + s0) = pk;
      }
  }
}

// =====================================================================
// O projection: out(FP32) = attn(B*S x 4096, bf16) @ wo(4096 x 4096)^T.
// =====================================================================
__global__ __launch_bounds__(256) void gemm_o_kernel(
    const u16* __restrict__ A, const u16* __restrict__ W,
    float* __restrict__ C) {
  __shared__ u16 As[128 * 32];
  __shared__ u16 Bs[128 * 32];
  const int mb = blockIdx.x, nb = blockIdx.y;
  f4 acc[4][4];
#pragma unroll
  for (int i = 0; i < 4; i++)
#pragma unroll
    for (int j = 0; j < 4; j++) acc[i][j] = (f4){0.f, 0.f, 0.f, 0.f};

  gemm_core(A, W, 4096, 4096, 4096, mb, nb, As, Bs, acc);

  const int tid = threadIdx.x, lane = tid & 63, wid = tid >> 6;
  const int l16 = lane & 15, quad = lane >> 4;
  const int wm = (wid >> 1) * 64, wn = (wid & 1) * 64;
#pragma unroll
  for (int mt = 0; mt < 4; mt++)
#pragma unroll
    for (int nt = 0; nt < 4; nt++) {
      const int n = nb * 128 + wn + nt * 16 + l16;
      const int m0 = mb * 128 + wm + mt * 16 + quad * 4;
#pragma unroll
      for (int r = 0; r < 4; r++)
        C[(size_t)(m0 + r) * 4096 + n] = acc[mt][nt][r];
    }
}

// =====================================================================
// RoPE in-place on bf16 (B,S,nh,128). thread = 8 elems (4 even/odd pairs).
// =====================================================================
__global__ void rope_kernel(u16* __restrict__ x, const u16* __restrict__ cs,
                            const u16* __restrict__ sn, int shift, float scale,
                            int nthreads) {
  const int t = blockIdx.x * 256 + threadIdx.x;
  if (t >= nthreads) return;
  const size_t e = (size_t)t * 8;
  const int d = (int)(e & 127);
  const int s = (int)((e >> shift) & 2047);
  uint4 xv = *(const uint4*)(x + e);
  uint4 cv = *(const uint4*)(cs + (size_t)s * 128 + d);
  uint4 sv = *(const uint4*)(sn + (size_t)s * 128 + d);
  u32 xw[4] = {xv.x, xv.y, xv.z, xv.w};
  u32 cw[4] = {cv.x, cv.y, cv.z, cv.w};
  u32 sw[4] = {sv.x, sv.y, sv.z, sv.w};
  u32 ow[4];
#pragma unroll
  for (int i = 0; i < 4; i++) {
    float x0 = b2f(xw[i] & 0xffff), x1 = b2f(xw[i] >> 16);
    float c = b2f(cw[i] & 0xffff);   // cos[s,2i] == cos[s,2i+1]
    float si = b2f(sw[i] & 0xffff);
    float o0 = (x0 * c - x1 * si) * scale;
    float o1 = (x1 * c + x0 * si) * scale;
    ow[i] = (u32)f2b(o0) | ((u32)f2b(o1) << 16);
  }
  uint4 ov = {ow[0], ow[1], ow[2], ow[3]};
  *(uint4*)(x + e) = ov;
}

// =====================================================================
// Flash attention (causal, GQA). QBLK=128: block = 128 queries of one head;
// 4 waves x 32 queries (2 halves of 16). Same K/V staging per 64-key tile
// as the proven round-0 structure, but block-tiles per CU HALVE (132 -> 68):
// the barrier-bounded staging stalls (measured ~50% of kernel time: busy
// counters sum to ~50% at 12 waves/CU) amortize over 2x the compute, and
// K/V L2 traffic halves. Swapped QK^T kept (lane-local softmax, 2 shfl per
// reduce); round-5's serial 16-deep add/max chains replaced with trees.
// accO[2][8] f4 lives in AGPRs (m97-style liveness; unlike the cross-
// barrier uint4 prefetch that spilled in rounds 2-3).
// __launch_bounds__(256,2): allow up to 256 VGPR; LDS (54272B) caps
// occupancy at 3 blocks/CU regardless.
// =====================================================================
__global__ __launch_bounds__(256, 2) void attn_kernel(
    const u16* __restrict__ q, const u16* __restrict__ k,
    const u16* __restrict__ vt, u16* __restrict__ attn) {
  __shared__ u16 Ks[64 * 136];    // [key][d], ld 136
  __shared__ u16 Vt[128 * 72];    // [d][key], ld 72
  __shared__ u16 Ps[4][32 * 72];  // per-wave [q][key], ld 72

  const int qblk = blockIdx.x, h = blockIdx.y, b = blockIdx.z;
  const int kv = h >> 2;
  const int tid = threadIdx.x, lane = tid & 63, wid = tid >> 6;
  const int l16 = lane & 15, quad = lane >> 4;

  const int wq0 = qblk * 128 + wid * 32;  // wave's first query

  // register-resident Q B-frags: aq[half][ds], query = wq0 + half*16 + l16
  bf8 aq[2][4];
#pragma unroll
  for (int half = 0; half < 2; half++) {
    const u16* qp =
        q + ((size_t)(b * 2048 + wq0 + half * 16 + l16) * 32 + h) * 128;
#pragma unroll
    for (int ds = 0; ds < 4; ds++)
      aq[half][ds] = *(const bf8*)(qp + ds * 32 + quad * 8);
  }

  f4 accO[2][8];
#pragma unroll
  for (int i = 0; i < 2; i++)
#pragma unroll
    for (int j = 0; j < 8; j++) accO[i][j] = (f4){0.f, 0.f, 0.f, 0.f};
  float m_[2] = {-1e30f, -1e30f};  // running max (per lane's query, per half)
  float l_[2] = {0.f, 0.f};        // running denom

  const u16* kp = k + ((size_t)(b * 2048) * 8 + kv) * 128;   // key stride 1024
  const u16* vp = vt + (size_t)(b * 8 + kv) * 128 * 2048;    // d stride 2048

  const int qmax = wq0 + 31;      // wave's last query (uniform per wave)
  const int NT = 2 * qblk + 2;    // 64-key tiles covering [0, qblk*128+128)

  for (int kt = 0; kt < NT; kt++) {
    const int key0 = kt * 64;
    __syncthreads();
    // stage K tile [64][128]: 4 reps x 256 threads x 8 u16
#pragma unroll
    for (int rep = 0; rep < 4; rep++) {
      const int e = rep * 2048 + tid * 8;
      const int row = e >> 7, col = e & 127;
      *(uint4*)(Ks + row * 136 + col) =
          *(const uint4*)(kp + (size_t)(key0 + row) * 1024 + col);
    }
    // stage Vt tile [128][64]
#pragma unroll
    for (int rep = 0; rep < 4; rep++) {
      const int e = rep * 2048 + tid * 8;
      const int row = e >> 6, col = e & 63;
      *(uint4*)(Vt + row * 72 + col) =
          *(const uint4*)(vp + (size_t)row * 2048 + key0 + col);
    }
    __syncthreads();

    if (key0 > qmax) continue;  // fully-masked tile for this wave (uniform)

    // ---- per half: QK^T (swapped) + softmax + P write ----
#pragma unroll
    for (int half = 0; half < 2; half++) {
      const int hq0 = wq0 + half * 16;
      f4 sc[4];  // sc[nt][r] = S[key0+nt*16+quad*4+r][q = hq0+l16]
#pragma unroll
      for (int nt = 0; nt < 4; nt++) {
        sc[nt] = (f4){0.f, 0.f, 0.f, 0.f};
        const int krow = nt * 16 + l16;
#pragma unroll
        for (int ds = 0; ds < 4; ds++) {
          bf8 bk = *(const bf8*)(Ks + krow * 136 + ds * 32 + quad * 8);
          sc[nt] = mfma16(bk, aq[half][ds], sc[nt]);
        }
      }

      // causal mask (only when this half's diagonal intersects the tile)
      if (key0 + 63 > hq0) {
        const int qglob = hq0 + l16;
#pragma unroll
        for (int nt = 0; nt < 4; nt++)
#pragma unroll
          for (int r = 0; r < 4; r++)
            if (key0 + nt * 16 + quad * 4 + r > qglob) sc[nt][r] = -1e30f;
      }

      // tile max: tree in-lane (depth 4) + 2 shfl quad-folds
      float mA = fmaxf(fmaxf(sc[0][0], sc[0][1]), fmaxf(sc[0][2], sc[0][3]));
      float mB = fmaxf(fmaxf(sc[1][0], sc[1][1]), fmaxf(sc[1][2], sc[1][3]));
      float mC = fmaxf(fmaxf(sc[2][0], sc[2][1]), fmaxf(sc[2][2], sc[2][3]));
      float mD = fmaxf(fmaxf(sc[3][0], sc[3][1]), fmaxf(sc[3][2], sc[3][3]));
      float mx = fmaxf(fmaxf(mA, mB), fmaxf(mC, mD));
      mx = fmaxf(mx, __shfl_xor(mx, 16, 64));
      mx = fmaxf(mx, __shfl_xor(mx, 32, 64));

      // defer-max (T13): rescale only when tile max grows by > 8 (exp2 dom)
      const bool grow = (mx - m_[half] > 8.f);
      float alpha = 1.f;
      if (grow) {
        alpha = exp2f(m_[half] - mx);
        m_[half] = mx;
        l_[half] *= alpha;
      }
      if (__ballot(grow)) {
#pragma unroll
        for (int r = 0; r < 4; r++) {
          const float ar = __shfl(alpha, (lane & 48) | (quad * 4 + r), 64);
#pragma unroll
          for (int nt = 0; nt < 8; nt++) accO[half][nt][r] *= ar;
        }
      }

      const float mr = m_[half];
      float psn[4];
#pragma unroll
      for (int nt = 0; nt < 4; nt++) {
        const float p0 = exp2f(sc[nt][0] - mr);
        const float p1 = exp2f(sc[nt][1] - mr);
        const float p2 = exp2f(sc[nt][2] - mr);
        const float p3 = exp2f(sc[nt][3] - mr);
        psn[nt] = (p0 + p1) + (p2 + p3);
        ushort4 pk;
        pk.x = f2b(p0);
        pk.y = f2b(p1);
        pk.z = f2b(p2);
        pk.w = f2b(p3);
        *(ushort4*)(&Ps[wid][(half * 16 + l16) * 72 + nt * 16 + quad * 4]) =
            pk;
      }
      float ps = (psn[0] + psn[1]) + (psn[2] + psn[3]);
      ps += __shfl_xor(ps, 16, 64);
      ps += __shfl_xor(ps, 32, 64);
      l_[half] += ps;
    }

    // ---- PV: accO[half][16q x 128d] += P[16x64] * V[64x128] ----
    bf8 ap[2][2];
#pragma unroll
    for (int half = 0; half < 2; half++)
#pragma unroll
      for (int ks = 0; ks < 2; ks++)
        ap[half][ks] = *(const bf8*)(&Ps[wid][(half * 16 + l16) * 72 +
                                             ks * 32 + quad * 8]);
#pragma unroll
    for (int ks = 0; ks < 2; ks++)
#pragma unroll
      for (int nt = 0; nt < 8; nt++) {
        bf8 bv = *(const bf8*)(Vt + (nt * 16 + l16) * 72 + ks * 32 + quad * 8);
        accO[0][nt] = mfma16(ap[0][ks], bv, accO[0][nt]);
        accO[1][nt] = mfma16(ap[1][ks], bv, accO[1][nt]);
      }
  }

  // ---- epilogue: attn[b][s][h][d] bf16 ----
#pragma unroll
  for (int half = 0; half < 2; half++) {
    const float invq = 1.0f / l_[half];
    float inv[4];
#pragma unroll
    for (int r = 0; r < 4; r++)
      inv[r] = __shfl(invq, (lane & 48) | (quad * 4 + r), 64);
#pragma unroll
    for (int nt = 0; nt < 8; nt++)
#pragma unroll
      for (int r = 0; r < 4; r++) {
        const int s = wq0 + half * 16 + quad * 4 + r;
        const int dcol = nt * 16 + l16;
        attn[((size_t)(b * 2048 + s) * 32 + h) * 128 + dcol] =
            f2b(accO[half][nt][r] * inv[r]);
      }
  }
}

// =====================================================================
extern "C" void kernel_launch(void* const* d_in, const int* in_sizes, int n_in,
                              void* d_out, int out_size, void* d_ws,
                              size_t ws_size, hipStream_t stream) {
  const u16* hidden = (const u16*)d_in[0];
  const u16* cosp = (const u16*)d_in[1];
  const u16* sinp = (const u16*)d_in[2];
  const u16* wq = (const u16*)d_in[3];
  const u16* wk = (const u16*)d_in[4];
  const u16* wv = (const u16*)d_in[5];
  const u16* wo = (const u16*)d_in[6];
  const u32* probe = (const u32*)d_in[1];  // cos[0] == 1.0
  float* out = (float*)d_out;              // fp32 output

  char* ws = (char*)d_ws;
  // hidden_n region is reused as attnb after gemm_qkv completes.
  u16* hidden_n = (u16*)(ws);                    // 32 MiB
  u16* attnb    = (u16*)(ws);                    // 32 MiB (alias, later)
  u16* qb       = (u16*)(ws + 33554432);         // 32 MiB
  u16* kb       = (u16*)(ws + 67108864);         //  8 MiB
  u16* vtb      = (u16*)(ws + 75497472);         //  8 MiB
  u16* wq_n     = (u16*)(ws + 83886080);         // 32 MiB
  u16* wk_n     = (u16*)(ws + 117440512);        //  8 MiB
  u16* wv_n     = (u16*)(ws + 125829120);        //  8 MiB
  u16* wo_n     = (u16*)(ws + 134217728);        // 32 MiB
  u16* cos_n    = (u16*)(ws + 167772160);        // 0.5 MiB
  u16* sin_n    = (u16*)(ws + 168296448);        // 0.5 MiB

  dim3 blk(256);
  // normalize all inputs to bf16 (runtime dtype detection via probe)
  convert_kernel<<<dim3(8192), blk, 0, stream>>>(hidden, hidden_n, probe,
                                                 2097152);
  convert_kernel<<<dim3(8192), blk, 0, stream>>>(wq, wq_n, probe, 2097152);
  convert_kernel<<<dim3(2048), blk, 0, stream>>>(wk, wk_n, probe, 524288);
  convert_kernel<<<dim3(2048), blk, 0, stream>>>(wv, wv_n, probe, 524288);
  convert_kernel<<<dim3(8192), blk, 0, stream>>>(wo, wo_n, probe, 2097152);
  convert_kernel<<<dim3(128), blk, 0, stream>>>(cosp, cos_n, probe, 32768);
  convert_kernel<<<dim3(128), blk, 0, stream>>>(sinp, sin_n, probe, 32768);

  gemm_qkv_kernel<<<dim3(32, 48), blk, 0, stream>>>(hidden_n, wq_n, wk_n, wv_n,
                                                    qb, kb, vtb);
  rope_kernel<<<dim3(8192), blk, 0, stream>>>(qb, cos_n, sin_n, 12, QSCALE,
                                              2097152);
  rope_kernel<<<dim3(2048), blk, 0, stream>>>(kb, cos_n, sin_n, 10, 1.0f,
                                              524288);
  attn_kernel<<<dim3(16, 32, 2), blk, 0, stream>>>(qb, kb, vtb, attnb);
  gemm_o_kernel<<<dim3(32, 32), blk, 0, stream>>>(attnb, wo_n, out);
}